// Round 1
// baseline (348.160 us; speedup 1.0000x reference)
//
#include <hip/hip_runtime.h>

// Problem constants (B, Cin, Cout, H, W) = (8, 256, 256, 128, 128)
#define BATCH 8
#define CIN   256
#define COUT  256
#define HH    128
#define WW    128
#define HW    (HH*WW)          // 16384

typedef __bf16 bf16x8 __attribute__((ext_vector_type(8)));
typedef float  f32x4  __attribute__((ext_vector_type(4)));

__device__ __forceinline__ unsigned short f2bf(float f) {
    unsigned u = __float_as_uint(f);
    unsigned r = (u + 0x7fffu + ((u >> 16) & 1u)) >> 16;   // round-to-nearest-even
    return (unsigned short)r;
}

// ---------------------------------------------------------------------------
// Kernel 1: W_b[b][o][c] = bf16(pw[o][c] + delta[b][o][c])
// 524288 floats total; each thread handles 4 via float4. grid=512, block=256.
// ---------------------------------------------------------------------------
__global__ __launch_bounds__(256) void prep_w_kernel(
    const float* __restrict__ delta, const float* __restrict__ pw,
    unsigned short* __restrict__ Wb)
{
    int i = blockIdx.x * 256 + threadIdx.x;          // quad index
    float4 d = *(const float4*)(delta + (size_t)i * 4);
    int j = (i * 4) & (COUT * CIN - 1);              // pw index (o*256+c)
    float4 p = *(const float4*)(pw + j);
    ushort4 r;
    r.x = f2bf(d.x + p.x);
    r.y = f2bf(d.y + p.y);
    r.z = f2bf(d.z + p.z);
    r.w = f2bf(d.w + p.w);
    *(ushort4*)(Wb + (size_t)i * 4) = r;
}

// ---------------------------------------------------------------------------
// Kernel 2: depthwise 3x3 conv (pad=1), fp32 compute, output bf16 TRANSPOSED
// to Tt[b][p][c] (p = h*128+w, c fastest) so the GEMM's B-fragment reads are
// K-contiguous ds_read_b128.
// Block: (ht, cb, b) = 8-row tile x 64-channel block of one image.
// Phase A: conv -> LDS tile [w=128][c=64] (+2 pad, dword row stride 33: odd).
// Phase B: read LDS transposed, write 128B-contiguous ushort2 runs to global.
// grid=(16,4,8), block=256.
// ---------------------------------------------------------------------------
__global__ __launch_bounds__(256) void dwconv_kernel(
    const float* __restrict__ x, const float* __restrict__ dw,
    unsigned short* __restrict__ Tt)
{
    __shared__ unsigned short tile[128 * 66];   // [w][c] row stride 66 ushorts
    __shared__ float kw[64 * 9];

    const int ht = blockIdx.x;   // 0..15 (8 rows each)
    const int cb = blockIdx.y;   // 0..3  (64 channels each)
    const int b  = blockIdx.z;   // 0..7
    const int tid = threadIdx.x;

    // stage this block's 64 channels' 3x3 weights: 576 floats = 144 float4
    if (tid < 144) {
        float4 v = *(const float4*)(dw + (size_t)cb * 576 + (size_t)tid * 4);
        *(float4*)(kw + tid * 4) = v;
    }
    __syncthreads();

    const int wq = tid & 31;     // w-quad: covers w0..w0+3
    const int cs = tid >> 5;     // 0..7 channel subgroup
    const int w0 = wq * 4;

    for (int hi = 0; hi < 8; ++hi) {
        const int h = ht * 8 + hi;

        for (int ci = 0; ci < 8; ++ci) {
            const int c = ci * 8 + cs;                       // local channel 0..63
            const float* xp = x + ((size_t)(b * CIN + cb * 64 + c)) * HW;
            const float* kc = kw + c * 9;
            float a0 = 0.f, a1 = 0.f, a2 = 0.f, a3 = 0.f;
            #pragma unroll
            for (int dy = 0; dy < 3; ++dy) {
                const int r = h + dy - 1;
                float4 v = {0.f, 0.f, 0.f, 0.f};
                if (r >= 0 && r < HH) v = *(const float4*)(xp + r * WW + w0);
                float lft = __shfl_up(v.w, 1);    // lane-1's last element
                float rgt = __shfl_down(v.x, 1);  // lane+1's first element
                if (wq == 0)  lft = 0.f;          // w=-1 pad
                if (wq == 31) rgt = 0.f;          // w=128 pad
                const float k0 = kc[dy * 3 + 0], k1 = kc[dy * 3 + 1], k2 = kc[dy * 3 + 2];
                a0 += k0 * lft + k1 * v.x + k2 * v.y;
                a1 += k0 * v.x + k1 * v.y + k2 * v.z;
                a2 += k0 * v.y + k1 * v.z + k2 * v.w;
                a3 += k0 * v.z + k1 * v.w + k2 * rgt;
            }
            const int base = w0 * 66 + c;
            tile[base]       = f2bf(a0);
            tile[base + 66]  = f2bf(a1);
            tile[base + 132] = f2bf(a2);
            tile[base + 198] = f2bf(a3);
        }
        __syncthreads();

        // Phase B: transposed write-out. lane pair covers 2 consecutive c.
        {
            const int cpair = tid & 31;   // c = 2*cpair .. 2*cpair+1
            const int wg    = tid >> 5;   // 8 w-groups of 16
            const size_t prow = (size_t)b * HW + (size_t)h * WW;
            #pragma unroll
            for (int wi = 0; wi < 16; ++wi) {
                const int w = wg * 16 + wi;
                unsigned v = *(const unsigned*)&tile[w * 66 + cpair * 2];
                *(unsigned*)&Tt[(prow + w) * CIN + cb * 64 + cpair * 2] = v;
            }
        }
        __syncthreads();
    }
}

// ---------------------------------------------------------------------------
// Kernel 3: per-batch GEMM  out[b][o][p] = sum_c Wb[b][o][c] * Tt[b][p][c]
// m97-style: 128x128 tile, BK=32, global_load_lds width=16 staging,
// 4 waves x (64x64), mfma_f32_16x16x32_bf16, fp32 epilogue.
// grid=(128 n-tiles, 2 m-tiles, 8 batch), block=256.
// ---------------------------------------------------------------------------
__global__ __launch_bounds__(256) void gemm_kernel(
    const unsigned short* __restrict__ Wb,
    const unsigned short* __restrict__ Tt,
    float* __restrict__ out)
{
    __shared__ unsigned short lA[128 * 32];
    __shared__ unsigned short lB[128 * 32];

    const int nt = blockIdx.x;   // 0..127
    const int mt = blockIdx.y;   // 0..1
    const int b  = blockIdx.z;   // 0..7
    const int tid = threadIdx.x;

    const unsigned short* Ab = Wb + ((size_t)b * COUT + mt * 128) * CIN;   // [128][256]
    const unsigned short* Bb = Tt + ((size_t)b * HW + nt * 128) * CIN;     // [128][256]

    const int lane = tid & 63;
    const int wv   = tid >> 6;
    const int wm   = (wv & 1) * 64;
    const int wn   = (wv >> 1) * 64;
    const int q    = lane >> 4;     // quad 0..3
    const int rrow = lane & 15;

    // staging map: round r covers rows r*64 + tid/4, 8 bf16 at col (tid&3)*8
    const int arow = tid >> 2;
    const int acol = (tid & 3) * 8;

    f32x4 acc[4][4] = {};

    for (int k0 = 0; k0 < CIN; k0 += 32) {
        #pragma unroll
        for (int r = 0; r < 2; ++r) {
            const int row = r * 64 + arow;
            const unsigned short* ga = Ab + (size_t)row * CIN + k0 + acol;
            const unsigned short* gb = Bb + (size_t)row * CIN + k0 + acol;
            __builtin_amdgcn_global_load_lds(
                (const __attribute__((address_space(1))) void*)ga,
                (__attribute__((address_space(3))) void*)(lA + (size_t)(r * 256 + tid) * 8),
                16, 0, 0);
            __builtin_amdgcn_global_load_lds(
                (const __attribute__((address_space(1))) void*)gb,
                (__attribute__((address_space(3))) void*)(lB + (size_t)(r * 256 + tid) * 8),
                16, 0, 0);
        }
        __syncthreads();

        bf16x8 af[4], bfv[4];
        #pragma unroll
        for (int i = 0; i < 4; ++i) {
            af[i]  = *(const bf16x8*)&lA[(wm + i * 16 + rrow) * 32 + q * 8];
            bfv[i] = *(const bf16x8*)&lB[(wn + i * 16 + rrow) * 32 + q * 8];
        }
        #pragma unroll
        for (int i = 0; i < 4; ++i)
            #pragma unroll
            for (int j = 0; j < 4; ++j)
                acc[i][j] = __builtin_amdgcn_mfma_f32_16x16x32_bf16(af[i], bfv[j], acc[i][j], 0, 0, 0);
        __syncthreads();
    }

    // epilogue: C/D map col=lane&15, row=quad*4+reg
    float* outp = out + ((size_t)b * COUT + mt * 128 + wm) * HW + (size_t)nt * 128 + wn;
    #pragma unroll
    for (int i = 0; i < 4; ++i)
        #pragma unroll
        for (int j = 0; j < 4; ++j)
            #pragma unroll
            for (int rr = 0; rr < 4; ++rr)
                outp[(size_t)(i * 16 + q * 4 + rr) * HW + j * 16 + rrow] = acc[i][j][rr];
}

// ---------------------------------------------------------------------------
extern "C" void kernel_launch(void* const* d_in, const int* in_sizes, int n_in,
                              void* d_out, int out_size, void* d_ws, size_t ws_size,
                              hipStream_t stream)
{
    const float* x     = (const float*)d_in[0];   // (8,256,128,128)
    const float* delta = (const float*)d_in[1];   // (8,256,256,1,1)
    const float* dw    = (const float*)d_in[2];   // (256,1,3,3)
    const float* pw    = (const float*)d_in[3];   // (256,256,1,1)
    float* out = (float*)d_out;                   // (8,256,128,128)

    // workspace layout: Tt bf16 [8][16384][256] = 64 MiB, then Wb bf16 [8][256][256] = 1 MiB
    unsigned short* Tt = (unsigned short*)d_ws;
    unsigned short* Wb = (unsigned short*)((char*)d_ws + (size_t)BATCH * HW * CIN * 2);

    prep_w_kernel<<<dim3(512), dim3(256), 0, stream>>>(delta, pw, Wb);
    dwconv_kernel<<<dim3(16, 4, 8), dim3(256), 0, stream>>>(x, dw, Tt);
    gemm_kernel<<<dim3(128, 2, 8), dim3(256), 0, stream>>>(Wb, Tt, out);
}

// Round 2
// 287.762 us; speedup vs baseline: 1.2099x; 1.2099x over previous
//
#include <hip/hip_runtime.h>

// Problem constants (B, Cin, Cout, H, W) = (8, 256, 256, 128, 128)
#define BATCH 8
#define CIN   256
#define COUT  256
#define HH    128
#define WW    128
#define HW    (HH*WW)          // 16384

typedef __bf16 bf16x8 __attribute__((ext_vector_type(8)));
typedef float  f32x4  __attribute__((ext_vector_type(4)));

__device__ __forceinline__ unsigned short f2bf(float f) {
    unsigned u = __float_as_uint(f);
    unsigned r = (u + 0x7fffu + ((u >> 16) & 1u)) >> 16;   // round-to-nearest-even
    return (unsigned short)r;
}

// ---------------------------------------------------------------------------
// Kernel 1: W_b[b][o][c] = bf16(pw[o][c] + delta[b][o][c])
// ---------------------------------------------------------------------------
__global__ __launch_bounds__(256) void prep_w_kernel(
    const float* __restrict__ delta, const float* __restrict__ pw,
    unsigned short* __restrict__ Wb)
{
    int i = blockIdx.x * 256 + threadIdx.x;          // quad index
    float4 d = *(const float4*)(delta + (size_t)i * 4);
    int j = (i * 4) & (COUT * CIN - 1);              // pw index (o*256+c)
    float4 p = *(const float4*)(pw + j);
    ushort4 r;
    r.x = f2bf(d.x + p.x);
    r.y = f2bf(d.y + p.y);
    r.z = f2bf(d.z + p.z);
    r.w = f2bf(d.w + p.w);
    *(ushort4*)(Wb + (size_t)i * 4) = r;
}

// ---------------------------------------------------------------------------
// Kernel 2 (v2): depthwise 3x3 conv (pad=1), fp32 compute, bf16 transposed
// output Tt[b][p][c]. ONE h-row per block for TLP: grid=(128 h, 4 cb, 8 b)
// = 4096 blocks (R0 had 512 -> occupancy 21%, latency-bound at 137 us).
// Phase A: conv -> LDS tile [w=128][c=64] (ushort row stride 66).
// Phase B: read LDS transposed, write ushort2 runs to global.
// ---------------------------------------------------------------------------
__global__ __launch_bounds__(256) void dwconv_kernel(
    const float* __restrict__ x, const float* __restrict__ dw,
    unsigned short* __restrict__ Tt)
{
    __shared__ unsigned short tile[128 * 66];   // [w][c] row stride 66 ushorts
    __shared__ float kw[64 * 9];

    const int h  = blockIdx.x;   // 0..127
    const int cb = blockIdx.y;   // 0..3  (64 channels each)
    const int b  = blockIdx.z;   // 0..7
    const int tid = threadIdx.x;

    // stage this block's 64 channels' 3x3 weights: 576 floats = 144 float4
    if (tid < 144) {
        float4 v = *(const float4*)(dw + (size_t)cb * 576 + (size_t)tid * 4);
        *(float4*)(kw + tid * 4) = v;
    }
    __syncthreads();

    const int wq = tid & 31;     // w-quad: covers w0..w0+3
    const int cs = tid >> 5;     // 0..7 channel subgroup
    const int w0 = wq * 4;

    for (int ci = 0; ci < 8; ++ci) {
        const int c = ci * 8 + cs;                       // local channel 0..63
        const float* xp = x + ((size_t)(b * CIN + cb * 64 + c)) * HW;
        const float* kc = kw + c * 9;
        float a0 = 0.f, a1 = 0.f, a2 = 0.f, a3 = 0.f;
        #pragma unroll
        for (int dy = 0; dy < 3; ++dy) {
            const int r = h + dy - 1;
            float4 v = {0.f, 0.f, 0.f, 0.f};
            if (r >= 0 && r < HH) v = *(const float4*)(xp + r * WW + w0);
            float lft = __shfl_up(v.w, 1);    // lane-1's last element
            float rgt = __shfl_down(v.x, 1);  // lane+1's first element
            if (wq == 0)  lft = 0.f;          // w=-1 pad
            if (wq == 31) rgt = 0.f;          // w=128 pad
            const float k0 = kc[dy * 3 + 0], k1 = kc[dy * 3 + 1], k2 = kc[dy * 3 + 2];
            a0 += k0 * lft + k1 * v.x + k2 * v.y;
            a1 += k0 * v.x + k1 * v.y + k2 * v.z;
            a2 += k0 * v.y + k1 * v.z + k2 * v.w;
            a3 += k0 * v.z + k1 * v.w + k2 * rgt;
        }
        const int base = w0 * 66 + c;
        tile[base]       = f2bf(a0);
        tile[base + 66]  = f2bf(a1);
        tile[base + 132] = f2bf(a2);
        tile[base + 198] = f2bf(a3);
    }
    __syncthreads();

    // Phase B: transposed write-out. lane pair covers 2 consecutive c.
    {
        const int cpair = tid & 31;   // c = 2*cpair .. 2*cpair+1
        const int wg    = tid >> 5;   // 8 w-groups of 16
        const size_t prow = (size_t)b * HW + (size_t)h * WW;
        #pragma unroll
        for (int wi = 0; wi < 16; ++wi) {
            const int w = wg * 16 + wi;
            unsigned v = *(const unsigned*)&tile[w * 66 + cpair * 2];
            *(unsigned*)&Tt[(prow + w) * CIN + cb * 64 + cpair * 2] = v;
        }
    }
}

// ---------------------------------------------------------------------------
// Kernel 3: per-batch GEMM  out[b][o][p] = sum_c Wb[b][o][c] * Tt[b][p][c]
// (unchanged from R0 — isolate it in next round's counters)
// ---------------------------------------------------------------------------
__global__ __launch_bounds__(256) void gemm_kernel(
    const unsigned short* __restrict__ Wb,
    const unsigned short* __restrict__ Tt,
    float* __restrict__ out)
{
    __shared__ unsigned short lA[128 * 32];
    __shared__ unsigned short lB[128 * 32];

    const int nt = blockIdx.x;   // 0..127
    const int mt = blockIdx.y;   // 0..1
    const int b  = blockIdx.z;   // 0..7
    const int tid = threadIdx.x;

    const unsigned short* Ab = Wb + ((size_t)b * COUT + mt * 128) * CIN;   // [128][256]
    const unsigned short* Bb = Tt + ((size_t)b * HW + nt * 128) * CIN;     // [128][256]

    const int lane = tid & 63;
    const int wv   = tid >> 6;
    const int wm   = (wv & 1) * 64;
    const int wn   = (wv >> 1) * 64;
    const int q    = lane >> 4;     // quad 0..3
    const int rrow = lane & 15;

    const int arow = tid >> 2;
    const int acol = (tid & 3) * 8;

    f32x4 acc[4][4] = {};

    for (int k0 = 0; k0 < CIN; k0 += 32) {
        #pragma unroll
        for (int r = 0; r < 2; ++r) {
            const int row = r * 64 + arow;
            const unsigned short* ga = Ab + (size_t)row * CIN + k0 + acol;
            const unsigned short* gb = Bb + (size_t)row * CIN + k0 + acol;
            __builtin_amdgcn_global_load_lds(
                (const __attribute__((address_space(1))) void*)ga,
                (__attribute__((address_space(3))) void*)(lA + (size_t)(r * 256 + tid) * 8),
                16, 0, 0);
            __builtin_amdgcn_global_load_lds(
                (const __attribute__((address_space(1))) void*)gb,
                (__attribute__((address_space(3))) void*)(lB + (size_t)(r * 256 + tid) * 8),
                16, 0, 0);
        }
        __syncthreads();

        bf16x8 af[4], bfv[4];
        #pragma unroll
        for (int i = 0; i < 4; ++i) {
            af[i]  = *(const bf16x8*)&lA[(wm + i * 16 + rrow) * 32 + q * 8];
            bfv[i] = *(const bf16x8*)&lB[(wn + i * 16 + rrow) * 32 + q * 8];
        }
        #pragma unroll
        for (int i = 0; i < 4; ++i)
            #pragma unroll
            for (int j = 0; j < 4; ++j)
                acc[i][j] = __builtin_amdgcn_mfma_f32_16x16x32_bf16(af[i], bfv[j], acc[i][j], 0, 0, 0);
        __syncthreads();
    }

    // epilogue: C/D map col=lane&15, row=quad*4+reg
    float* outp = out + ((size_t)b * COUT + mt * 128 + wm) * HW + (size_t)nt * 128 + wn;
    #pragma unroll
    for (int i = 0; i < 4; ++i)
        #pragma unroll
        for (int j = 0; j < 4; ++j)
            #pragma unroll
            for (int rr = 0; rr < 4; ++rr)
                outp[(size_t)(i * 16 + q * 4 + rr) * HW + j * 16 + rrow] = acc[i][j][rr];
}

// ---------------------------------------------------------------------------
extern "C" void kernel_launch(void* const* d_in, const int* in_sizes, int n_in,
                              void* d_out, int out_size, void* d_ws, size_t ws_size,
                              hipStream_t stream)
{
    const float* x     = (const float*)d_in[0];   // (8,256,128,128)
    const float* delta = (const float*)d_in[1];   // (8,256,256,1,1)
    const float* dw    = (const float*)d_in[2];   // (256,1,3,3)
    const float* pw    = (const float*)d_in[3];   // (256,256,1,1)
    float* out = (float*)d_out;                   // (8,256,128,128)

    // workspace: Tt bf16 [8][16384][256] = 64 MiB, then Wb bf16 [8][256][256] = 1 MiB
    unsigned short* Tt = (unsigned short*)d_ws;
    unsigned short* Wb = (unsigned short*)((char*)d_ws + (size_t)BATCH * HW * CIN * 2);

    prep_w_kernel<<<dim3(512), dim3(256), 0, stream>>>(delta, pw, Wb);
    dwconv_kernel<<<dim3(128, 4, 8), dim3(256), 0, stream>>>(x, dw, Tt);
    gemm_kernel<<<dim3(128, 2, 8), dim3(256), 0, stream>>>(Wb, Tt, out);
}